// Round 1
// baseline (1676.225 us; speedup 1.0000x reference)
//
#include <hip/hip_runtime.h>

// ---- dims (fixed by problem) ----
#define B    32
#define P    196
#define ENC  2048
#define DEC  512
#define ATT  512
#define E    256
#define V    30000
#define VPAD 30080   // V padded to multiple of 128 for the final GEMM
#define L    21
#define T    20      // L-1

typedef unsigned short u16;
typedef __bf16 bf16x8 __attribute__((ext_vector_type(8)));
typedef float  f32x4  __attribute__((ext_vector_type(4)));

__device__ __forceinline__ u16 f2bf(float f) {
    union { float f; unsigned int i; } v; v.f = f;
    unsigned int i = v.i;
    return (u16)((i + 0x7fffu + ((i >> 16) & 1u)) >> 16);
}
__device__ __forceinline__ float bf2f(u16 u) {
    union { unsigned int i; float f; } v; v.i = ((unsigned int)u) << 16; return v.f;
}
__device__ __forceinline__ float wave_sum(float v) {
    #pragma unroll
    for (int o = 32; o > 0; o >>= 1) v += __shfl_down(v, o, 64);
    return v;  // lane 0 holds sum
}
__device__ __forceinline__ float sigf(float x) { return 1.0f / (1.0f + expf(-x)); }

// async global->LDS, 16B per lane; LDS dest is wave-uniform base + lane*16
__device__ __forceinline__ void gl2lds16(const u16* g, char* l) {
    __builtin_amdgcn_global_load_lds(
        (const __attribute__((address_space(1))) void*)g,
        (__attribute__((address_space(3))) void*)l, 16, 0, 0);
}

// ---- once: f32 -> bf16 conversion (4 elems/thread) ----
__global__ void k_f2b4(const float* __restrict__ s, u16* __restrict__ d, int n4) {
    int i = blockIdx.x * 256 + threadIdx.x;
    if (i < n4) {
        float4 v = reinterpret_cast<const float4*>(s)[i];
        ushort4 o;
        o.x = f2bf(v.x); o.y = f2bf(v.y); o.z = f2bf(v.z); o.w = f2bf(v.w);
        reinterpret_cast<ushort4*>(d)[i] = o;
    }
}

__global__ void k_zero16(u16* __restrict__ d, int n) {
    int i = blockIdx.x * 256 + threadIdx.x;
    if (i < n) d[i] = 0;
}

// ---- once: mean over P of encoder_out (f32) -> f32 [B,ENC] ----
__global__ void k_mean(const float* __restrict__ enc, float* __restrict__ mean) {
    int idx = blockIdx.x * 256 + threadIdx.x;        // 65536
    int b = idx >> 11, e = idx & 2047;
    const float* p = enc + (size_t)b * P * ENC + e;
    float s = 0.f;
    for (int i = 0; i < P; i++) s += p[(size_t)i * ENC];
    mean[idx] = s * (1.0f / 196.0f);
}

// ---- once: h0/c0 = mean @ W^T + b  (f32 dot, wave per output) ----
__global__ void k_h0c0(const float* __restrict__ mean,
                       const float* __restrict__ Wh0, const float* __restrict__ bh0,
                       const float* __restrict__ Wc0, const float* __restrict__ bc0,
                       u16* __restrict__ h, float* __restrict__ c) {
    int wid = (blockIdx.x * 256 + threadIdx.x) >> 6;
    int lane = threadIdx.x & 63;
    int b = wid >> 10, j = wid & 1023;
    bool is_h = j < DEC;
    int jj = is_h ? j : j - DEC;
    const float* W = is_h ? Wh0 : Wc0;
    const float* mrow = mean + b * ENC;
    const float* wrow = W + (size_t)jj * ENC;
    float acc = 0.f;
    #pragma unroll
    for (int kk = 0; kk < 4; kk++) {
        int k = kk * 512 + lane * 8;
        float4 a0 = *reinterpret_cast<const float4*>(mrow + k);
        float4 a1 = *reinterpret_cast<const float4*>(mrow + k + 4);
        float4 w0 = *reinterpret_cast<const float4*>(wrow + k);
        float4 w1 = *reinterpret_cast<const float4*>(wrow + k + 4);
        acc += a0.x * w0.x + a0.y * w0.y + a0.z * w0.z + a0.w * w0.w;
        acc += a1.x * w1.x + a1.y * w1.y + a1.z * w1.z + a1.w * w1.w;
    }
    acc = wave_sum(acc);
    if (lane == 0) {
        acc += is_h ? bh0[jj] : bc0[jj];
        if (is_h) h[b * DEC + jj] = f2bf(acc);
        else      c[b * DEC + jj] = acc;
    }
}

// ---- tiled 128x128 GEMM, BK=64, 4 waves, global_load_lds + XOR swizzle ----
// C[M,N] = A[M,K] @ Bmat[N,K]^T + bias.  Row-major bf16 A/B, K elems/row.
// PREDS=false: att1 epilogue (C stride ATT).  PREDS=true: preds epilogue.
template<int K, bool PREDS>
__global__ __launch_bounds__(256) void k_gemm128(
        const u16* __restrict__ A, const u16* __restrict__ Bmat,
        const float* __restrict__ bias, float* __restrict__ Cout) {
    __shared__ char smem[32768];
    char* As = smem;            // [128 rows][128 B], swizzled
    char* Bs = smem + 16384;
    int bid = blockIdx.x;
    int bm, bn;
    if constexpr (PREDS) { bm = bid % 5; bn = bid / 5; }   // B-panel reuse across 5 m-blocks
    else                 { bm = bid >> 2; bn = bid & 3; }  // A-panel reuse across 4 n-blocks
    int tid  = threadIdx.x;
    int w    = tid >> 6, lane = tid & 63;
    int quad = lane >> 4, l16 = lane & 15;
    int wave_m = (w >> 1) * 64, wave_n = (w & 1) * 64;

    // staging constants: phys LDS slot o = i*4096 + w*1024 + lane*16
    // phys row r = o>>7; logical col-byte cb = (o&127) ^ ((r&7)<<4)  (involution)
    int rl = lane >> 3;                        // r&7
    int ce = (((lane & 7) << 4) ^ (rl << 4)) >> 1;   // element offset in row
    const u16* srcA[4]; const u16* srcB[4];
    char* dstA[4]; char* dstB[4];
    #pragma unroll
    for (int i = 0; i < 4; i++) {
        int r = i * 32 + w * 8 + rl;
        srcA[i] = A    + (size_t)(bm * 128 + r) * K + ce;
        srcB[i] = Bmat + (size_t)(bn * 128 + r) * K + ce;
        dstA[i] = As + i * 4096 + w * 1024;
        dstB[i] = Bs + i * 4096 + w * 1024;
    }

    f32x4 acc[4][4] = {};
    int swz = (l16 & 7) << 4;
    for (int kt = 0; kt < K / 64; kt++) {
        int koff = kt * 64;
        #pragma unroll
        for (int i = 0; i < 4; i++) {
            gl2lds16(srcA[i] + koff, dstA[i]);
            gl2lds16(srcB[i] + koff, dstB[i]);
        }
        __syncthreads();   // drains vmcnt before barrier
        #pragma unroll
        for (int ks = 0; ks < 2; ks++) {
            int cb = ks * 64 + quad * 16;
            bf16x8 av[4], bv[4];
            #pragma unroll
            for (int mi = 0; mi < 4; mi++) {
                int r = wave_m + mi * 16 + l16;
                av[mi] = *reinterpret_cast<const bf16x8*>(As + r * 128 + (cb ^ swz));
            }
            #pragma unroll
            for (int ni = 0; ni < 4; ni++) {
                int r = wave_n + ni * 16 + l16;
                bv[ni] = *reinterpret_cast<const bf16x8*>(Bs + r * 128 + (cb ^ swz));
            }
            #pragma unroll
            for (int mi = 0; mi < 4; mi++)
                #pragma unroll
                for (int ni = 0; ni < 4; ni++)
                    acc[mi][ni] = __builtin_amdgcn_mfma_f32_16x16x32_bf16(
                        av[mi], bv[ni], acc[mi][ni], 0, 0, 0);
        }
        __syncthreads();
    }

    #pragma unroll
    for (int mi = 0; mi < 4; mi++) {
        #pragma unroll
        for (int ni = 0; ni < 4; ni++) {
            int nn = bn * 128 + wave_n + ni * 16 + l16;
            float bv = (!PREDS || nn < V) ? bias[nn] : 0.f;
            #pragma unroll
            for (int r = 0; r < 4; r++) {
                int mm = bm * 128 + wave_m + mi * 16 + quad * 4 + r;
                if constexpr (PREDS) {
                    if (nn < V) {
                        int b = mm & 31, t = mm >> 5;   // row = t*B + b
                        Cout[(size_t)b * T * V + (size_t)t * V + nn] = acc[mi][ni][r] + bv;
                    }
                } else {
                    Cout[(size_t)mm * ATT + nn] = acc[mi][ni][r] + bv;
                }
            }
        }
    }
}

// ---- per step (fused): att2 + e + softmax.  grid=B blocks, 1024 threads ----
__global__ __launch_bounds__(1024) void k_att_step(
        const u16* __restrict__ h, const float* __restrict__ Wd,
        const float* __restrict__ bd, const float* __restrict__ att1,
        const float* __restrict__ Wf, const float* __restrict__ bfa,
        float* __restrict__ alpha, float* __restrict__ out_alpha, int t) {
    __shared__ float att2s[ATT];
    __shared__ float es[256];
    __shared__ float red[256];
    int b = blockIdx.x;
    int tid = threadIdx.x, w = tid >> 6, lane = tid & 63;

    // phase 0: att2[a] = h[b,:] . Wd[a,:] + bd[a]   (wave w owns a = w*32..w*32+31)
    bf16x8 hv = *reinterpret_cast<const bf16x8*>(h + b * DEC + lane * 8);
    float hf[8];
    #pragma unroll
    for (int j = 0; j < 8; j++) hf[j] = (float)hv[j];
    for (int ii = 0; ii < 32; ii++) {
        int a = (w << 5) + ii;
        const float* wd = Wd + (size_t)a * DEC + (lane << 3);
        float4 w0 = *reinterpret_cast<const float4*>(wd);
        float4 w1 = *reinterpret_cast<const float4*>(wd + 4);
        float acc = hf[0]*w0.x + hf[1]*w0.y + hf[2]*w0.z + hf[3]*w0.w
                  + hf[4]*w1.x + hf[5]*w1.y + hf[6]*w1.z + hf[7]*w1.w;
        acc = wave_sum(acc);
        if (lane == 0) att2s[a] = acc + bd[a];
    }
    if (tid >= P && tid < 256) es[tid] = -1e30f;
    __syncthreads();

    // phase 1: e[p] = sum_a relu(att1[b,p,a]+att2[a])*Wf[a] + bf  (wave w: p = w, w+16, ...)
    float4 s0 = *reinterpret_cast<const float4*>(att2s + (lane << 3));
    float4 s1 = *reinterpret_cast<const float4*>(att2s + (lane << 3) + 4);
    const float* wfp = Wf + (lane << 3);
    float4 wf0 = *reinterpret_cast<const float4*>(wfp);
    float4 wf1 = *reinterpret_cast<const float4*>(wfp + 4);
    for (int p = w; p < P; p += 16) {
        const float* a1 = att1 + ((size_t)b * P + p) * ATT + (lane << 3);
        float4 x0 = *reinterpret_cast<const float4*>(a1);
        float4 x1 = *reinterpret_cast<const float4*>(a1 + 4);
        float acc;
        acc  = fmaxf(x0.x + s0.x, 0.f) * wf0.x;
        acc += fmaxf(x0.y + s0.y, 0.f) * wf0.y;
        acc += fmaxf(x0.z + s0.z, 0.f) * wf0.z;
        acc += fmaxf(x0.w + s0.w, 0.f) * wf0.w;
        acc += fmaxf(x1.x + s1.x, 0.f) * wf1.x;
        acc += fmaxf(x1.y + s1.y, 0.f) * wf1.y;
        acc += fmaxf(x1.z + s1.z, 0.f) * wf1.z;
        acc += fmaxf(x1.w + s1.w, 0.f) * wf1.w;
        acc = wave_sum(acc);
        if (lane == 0) es[p] = acc + bfa[0];
    }
    __syncthreads();

    // phase 2: softmax over es[0..195]
    float v = (tid < 256) ? es[tid] : -1e30f;
    if (tid < 256) red[tid] = v;
    __syncthreads();
    for (int s = 128; s > 0; s >>= 1) {
        if (tid < s) red[tid] = fmaxf(red[tid], red[tid + s]);
        __syncthreads();
    }
    float mx = red[0];
    __syncthreads();
    float ev = (tid < P) ? expf(v - mx) : 0.f;
    if (tid < 256) red[tid] = ev;
    __syncthreads();
    for (int s = 128; s > 0; s >>= 1) {
        if (tid < s) red[tid] += red[tid + s];
        __syncthreads();
    }
    float inv = 1.0f / red[0];
    if (tid < P) {
        float a = ev * inv;
        alpha[b * P + tid] = a;
        out_alpha[(size_t)b * T * P + (size_t)t * P + tid] = a;
    }
}

// ---- per step: awe + build x = [emb_t, awe] as bf16 [B, E+ENC] ----
__global__ void k_awe(const float* __restrict__ alpha, const u16* __restrict__ enc_bf,
                      const float* __restrict__ emb, const int* __restrict__ captions,
                      u16* __restrict__ x, int t) {
    __shared__ float al[P];
    int b = blockIdx.x >> 3, chunk = blockIdx.x & 7, tid = threadIdx.x;
    if (tid < P) al[tid] = alpha[b * P + tid];
    __syncthreads();
    int ec = chunk * 256 + tid;
    const u16* ep = enc_bf + (size_t)b * P * ENC + ec;
    float acc = 0.f;
    for (int p = 0; p < P; p++) acc += al[p] * bf2f(ep[(size_t)p * ENC]);
    x[b * (E + ENC) + E + ec] = f2bf(acc);
    if (chunk == 0) {
        int cap = captions[b * L + t];
        x[b * (E + ENC) + tid] = f2bf(emb[(size_t)cap * E + tid]);
    }
}

// ---- per step (fused): gates MFMA + LSTM cell.  grid=64, 256 threads ----
// block = (mt, jt): m-tile mt (16 rows of B), d-tile jt (16 of DEC).
// wave wg computes gate section wg at cols wg*512 + jt*16.  Cell is block-local.
__global__ __launch_bounds__(256) void k_gates_cell(
        const u16* __restrict__ x, const u16* __restrict__ h,
        const u16* __restrict__ Wih, const float* __restrict__ bih,
        const u16* __restrict__ Whh, const float* __restrict__ bhh,
        float* __restrict__ c, u16* __restrict__ hout,
        u16* __restrict__ hall, int t) {
    __shared__ float gsm[4][16][17];
    int bid = blockIdx.x;
    int mt = bid >> 5, jt = bid & 31;
    int tid = threadIdx.x, wg = tid >> 6, lane = tid & 63;
    int quad = lane >> 4, l16 = lane & 15;
    int m = mt * 16 + l16;                  // batch row
    int n = wg * 512 + jt * 16 + l16;       // gate column
    const int KX = E + ENC;                 // 2304
    f32x4 acc = {0.f, 0.f, 0.f, 0.f};
    for (int ks = 0; ks < KX / 32; ks++) {
        int k = ks * 32 + quad * 8;
        bf16x8 a  = *reinterpret_cast<const bf16x8*>(x   + m * KX + k);
        bf16x8 bb = *reinterpret_cast<const bf16x8*>(Wih + (size_t)n * KX + k);
        acc = __builtin_amdgcn_mfma_f32_16x16x32_bf16(a, bb, acc, 0, 0, 0);
    }
    for (int ks = 0; ks < DEC / 32; ks++) {
        int k = ks * 32 + quad * 8;
        bf16x8 a  = *reinterpret_cast<const bf16x8*>(h   + m * DEC + k);
        bf16x8 bb = *reinterpret_cast<const bf16x8*>(Whh + (size_t)n * DEC + k);
        acc = __builtin_amdgcn_mfma_f32_16x16x32_bf16(a, bb, acc, 0, 0, 0);
    }
    #pragma unroll
    for (int r = 0; r < 4; r++)
        gsm[wg][quad * 4 + r][l16] = acc[r] + bih[n] + bhh[n];
    __syncthreads();
    // cell: thread -> (row, col) of this block's 16x16 (b, d) patch
    int row = tid >> 4, col = tid & 15;
    int bI = mt * 16 + row, d = jt * 16 + col;
    float gi = sigf(gsm[0][row][col]);
    float gf = sigf(gsm[1][row][col]);
    float gg = tanhf(gsm[2][row][col]);
    float go = sigf(gsm[3][row][col]);
    int idx = bI * DEC + d;
    float cn = gf * c[idx] + gi * gg;
    c[idx] = cn;
    u16 hb = f2bf(go * tanhf(cn));
    hout[idx] = hb;                                  // next step's h (ping-pong)
    hall[(size_t)t * B * DEC + idx] = hb;            // row t*B+b for batched preds
}

extern "C" void kernel_launch(void* const* d_in, const int* in_sizes, int n_in,
                              void* d_out, int out_size, void* d_ws, size_t ws_size,
                              hipStream_t stream) {
    const float* enc  = (const float*)d_in[0];
    const int*   caps = (const int*)d_in[1];
    // d_in[2] caption_lengths: unused by reference output
    const float* emb  = (const float*)d_in[3];
    const float* We   = (const float*)d_in[4];
    const float* be   = (const float*)d_in[5];
    const float* Wd   = (const float*)d_in[6];
    const float* bd   = (const float*)d_in[7];
    const float* Wf   = (const float*)d_in[8];
    const float* bfa  = (const float*)d_in[9];
    const float* Wih  = (const float*)d_in[10];
    const float* bih  = (const float*)d_in[11];
    const float* Whh  = (const float*)d_in[12];
    const float* bhh  = (const float*)d_in[13];
    const float* Wfc  = (const float*)d_in[14];
    const float* bfc  = (const float*)d_in[15];
    const float* Wh0  = (const float*)d_in[16];
    const float* bh0  = (const float*)d_in[17];
    const float* Wc0  = (const float*)d_in[18];
    const float* bc0  = (const float*)d_in[19];

    float* out_preds = (float*)d_out;
    float* out_alpha = (float*)d_out + (size_t)B * T * V;

    char* w = (char*)d_ws;
    size_t off = 0;
    auto carve = [&](size_t bytes) -> void* {
        void* p = w + off;
        off = (off + bytes + 255) & ~(size_t)255;
        return p;
    };
    u16*   enc_bf = (u16*)  carve((size_t)B * P * ENC * 2);        // 25.7 MB
    u16*   We_bf  = (u16*)  carve((size_t)ATT * ENC * 2);          //  2.1 MB
    u16*   Wih_bf = (u16*)  carve((size_t)4 * DEC * (E + ENC) * 2);//  9.4 MB
    u16*   Whh_bf = (u16*)  carve((size_t)4 * DEC * DEC * 2);      //  2.1 MB
    u16*   Wfc_bf = (u16*)  carve((size_t)VPAD * DEC * 2);         // 30.8 MB (padded)
    float* att1   = (float*)carve((size_t)B * P * ATT * 4);        // 12.85 MB
    float* meanb  = (float*)carve((size_t)B * ENC * 4);
    float* alpha  = (float*)carve((size_t)B * P * 4);
    u16*   xbuf   = (u16*)  carve((size_t)B * (E + ENC) * 2);
    u16*   hb0    = (u16*)  carve((size_t)B * DEC * 2);
    u16*   hb1    = (u16*)  carve((size_t)B * DEC * 2);
    float* cbuf   = (float*)carve((size_t)B * DEC * 4);
    u16*   hall   = (u16*)  carve((size_t)T * B * DEC * 2);        // 0.66 MB
    (void)ws_size; (void)n_in; (void)in_sizes; (void)out_size;

    // one-time: bf16 conversions
    k_f2b4<<<(B * P * ENC) / 1024, 256, 0, stream>>>(enc, enc_bf, (B * P * ENC) / 4);
    k_f2b4<<<(ATT * ENC) / 1024, 256, 0, stream>>>(We, We_bf, (ATT * ENC) / 4);
    k_f2b4<<<(4 * DEC * (E + ENC)) / 1024, 256, 0, stream>>>(Wih, Wih_bf, (4 * DEC * (E + ENC)) / 4);
    k_f2b4<<<(4 * DEC * DEC) / 1024, 256, 0, stream>>>(Whh, Whh_bf, (4 * DEC * DEC) / 4);
    k_f2b4<<<(V * DEC) / 1024, 256, 0, stream>>>(Wfc, Wfc_bf, (V * DEC) / 4);
    k_zero16<<<((VPAD - V) * DEC) / 256, 256, 0, stream>>>(Wfc_bf + (size_t)V * DEC, (VPAD - V) * DEC);

    // init phase
    k_mean<<<(B * ENC) / 256, 256, 0, stream>>>(enc, meanb);
    k_h0c0<<<(B * 2 * DEC * 64) / 256, 256, 0, stream>>>(meanb, Wh0, bh0, Wc0, bc0, hb0, cbuf);
    // att1 = enc @ We^T + be : [6272, 2048] x [512, 2048]^T, tiled GEMM
    k_gemm128<ENC, false><<<(B * P / 128) * (ATT / 128), 256, 0, stream>>>(enc_bf, We_bf, be, att1);

    // 20 sequential decode steps, 3 launches each
    for (int t = 0; t < T; t++) {
        const u16* hin = (t & 1) ? hb1 : hb0;
        u16* hnx = (t & 1) ? hb0 : hb1;
        k_att_step  <<<B, 1024, 0, stream>>>(hin, Wd, bd, att1, Wf, bfa, alpha, out_alpha, t);
        k_awe       <<<B * 8, 256, 0, stream>>>(alpha, enc_bf, emb, caps, xbuf, t);
        k_gates_cell<<<64, 256, 0, stream>>>(xbuf, hin, Wih_bf, bih, Whh_bf, bhh,
                                             cbuf, hnx, hall, t);
    }

    // batched preds: [T*B, DEC] @ Wfc^T -> out[b, t, :]
    k_gemm128<DEC, true><<<5 * (VPAD / 128), 256, 0, stream>>>(hall, Wfc_bf, bfc, out_preds);
}